// Round 1
// baseline (6483.508 us; speedup 1.0000x reference)
//
#include <hip/hip_runtime.h>

// Neural ODE RK4 scan: 1024 independent batch rows, one per block.
// Weights held entirely in VGPRs (128 regs/lane); LDS only for broadcasts
// and the per-eval 4-wave partial-sum exchange.

#define NB 1024   // batch
#define ND 64     // dim
#define NH 256    // hidden
#define NSTEPS 999

__device__ __forceinline__ float fast_tanh(float x) {
    // tanh(x) = 1 - 2/(1+e^{2x}); v_exp_f32 + v_rcp_f32, ~1e-7 abs error
    float e = __expf(2.0f * x);
    float r = __builtin_amdgcn_rcpf(e + 1.0f);
    return 1.0f - 2.0f * r;
}

__global__ __launch_bounds__(256, 3)
void node_rk4_kernel(const float* __restrict__ y0,
                     const float* __restrict__ t,
                     const float* __restrict__ W1,
                     const float* __restrict__ b1,
                     const float* __restrict__ W2,
                     const float* __restrict__ b2,
                     float* __restrict__ out)
{
    const int row = blockIdx.x;
    const int tid = threadIdx.x;
    const int w   = tid >> 6;        // wave 0..3 -> hidden slice
    const int l   = tid & 63;        // lane -> dim index / hidden offset
    const int j   = (w << 6) + l;    // owned hidden unit

    __shared__ __align__(16) float xbuf[4][ND];     // wave-private input bcast
    __shared__ __align__(16) float abuf[4][ND];     // wave-private activation bcast
    __shared__ __align__(16) float part[2][ND][4];  // cross-wave partials (dbuf)

    // ---- preload weight slices into VGPRs (once; L2/L3-served) ----
    float W1c[ND];                    // W1[:, j] : column for owned hidden unit
    #pragma unroll
    for (int i = 0; i < ND; ++i) W1c[i] = W1[i * NH + j];
    float W2r[ND];                    // W2[64w+jj, l] : rows of owned j-slice
    #pragma unroll
    for (int jj = 0; jj < ND; ++jj) W2r[jj] = W2[((w << 6) + jj) * ND + l];
    const float b1l = b1[j];
    const float b2l = b2[l];

    float y = y0[row * ND + l];
    if (w == 0) out[row * ND + l] = y;   // step-0 output = y0

    int pb = 0;  // part double-buffer selector (wave-uniform)

    // func(y) = tanh(y@W1+b1)@W2+b2, input/output distributed elem-per-lane,
    // computed redundantly per wave so every wave holds the full k vector.
    auto F = [&](float x) -> float {
        xbuf[w][l] = x;
        asm volatile("s_waitcnt lgkmcnt(0)" ::: "memory");  // within-wave RAW
        const float4* xv4 = reinterpret_cast<const float4*>(&xbuf[w][0]);
        float h0 = b1l, h1 = 0.0f;    // 2 chains: cover 4cy FMA latency
        #pragma unroll
        for (int q = 0; q < 16; ++q) {
            float4 xv = xv4[q];       // broadcast read (uniform addr)
            h0 = fmaf(W1c[4*q+0], xv.x, h0);
            h1 = fmaf(W1c[4*q+1], xv.y, h1);
            h0 = fmaf(W1c[4*q+2], xv.z, h0);
            h1 = fmaf(W1c[4*q+3], xv.w, h1);
        }
        float a = fast_tanh(h0 + h1);
        abuf[w][l] = a;
        asm volatile("s_waitcnt lgkmcnt(0)" ::: "memory");
        const float4* av4 = reinterpret_cast<const float4*>(&abuf[w][0]);
        float p0 = 0.0f, p1 = 0.0f;
        #pragma unroll
        for (int q = 0; q < 16; ++q) {
            float4 av = av4[q];       // broadcast read
            p0 = fmaf(av.x, W2r[4*q+0], p0);
            p1 = fmaf(av.y, W2r[4*q+1], p1);
            p0 = fmaf(av.z, W2r[4*q+2], p0);
            p1 = fmaf(av.w, W2r[4*q+3], p1);
        }
        part[pb][l][w] = p0 + p1;
        __syncthreads();              // the ONLY barrier per eval
        float4 pv = *reinterpret_cast<const float4*>(&part[pb][l][0]);
        pb ^= 1;                      // dbuf: WAR separated by next eval's barrier
        return (pv.x + pv.y) + (pv.z + pv.w) + b2l;
    };

    for (int s = 0; s < NSTEPS; ++s) {
        float t0 = t[s];              // uniform scalar loads
        float h  = t[s + 1] - t0;
        float hh = 0.5f * h;
        float k1 = F(y);
        float k2 = F(fmaf(hh, k1, y));
        float k3 = F(fmaf(hh, k2, y));
        float k4 = F(fmaf(h,  k3, y));
        y = fmaf(h * (1.0f / 6.0f), (k1 + k4) + 2.0f * (k2 + k3), y);
        if (w == 0)                   // waves hold identical y; store once
            out[(size_t)(s + 1) * (NB * ND) + row * ND + l] = y;
    }
}

extern "C" void kernel_launch(void* const* d_in, const int* in_sizes, int n_in,
                              void* d_out, int out_size, void* d_ws, size_t ws_size,
                              hipStream_t stream) {
    const float* y0 = (const float*)d_in[0];
    const float* t  = (const float*)d_in[1];
    const float* W1 = (const float*)d_in[2];
    const float* b1 = (const float*)d_in[3];
    const float* W2 = (const float*)d_in[4];
    const float* b2 = (const float*)d_in[5];
    float* out = (float*)d_out;
    hipLaunchKernelGGL(node_rk4_kernel, dim3(NB), dim3(256), 0, stream,
                       y0, t, W1, b1, W2, b2, out);
}

// Round 3
// 5996.001 us; speedup vs baseline: 1.0813x; 1.0813x over previous
//
#include <hip/hip_runtime.h>

// Neural ODE RK4 scan: 1024 independent batch rows, one block (4 waves) per row.
// Wave w owns hidden slice j in [64w, 64w+64); weights live in VGPRs
// (float4 W1c[16] + W2r[16] = 128 regs/lane, compile-time-indexed only).
// LDS: wave-private broadcast buffers (no barrier needed - same-wave DS ops
// are in-order) + stride-5 conflict-free cross-wave partial exchange
// (1 raw s_barrier per eval; no vmcnt drain so output stores float).

#define NB 1024
#define ND 64
#define NH 256

__device__ __forceinline__ float fast_tanh(float x) {
    // tanh(x) = 1 - 2/(1+e^{2x})
    float e = __expf(2.0f * x);
    float r = __builtin_amdgcn_rcpf(e + 1.0f);
    return 1.0f - 2.0f * r;
}

// lgkmcnt(0): our part-write is in LDS before the barrier; no vmcnt drain.
#define BLOCK_SYNC() do {                                        \
    asm volatile("s_waitcnt lgkmcnt(0)" ::: "memory");           \
    __builtin_amdgcn_s_barrier();                                \
    asm volatile("" ::: "memory");                               \
} while (0)

// One func eval: KOUT = (tanh(XIN@W1+b1)@W2+b2)[l], XIN/KOUT elem-per-lane,
// replicated across the 4 waves (each holds the full vector).
#define EVAL(XIN, KOUT) do {                                     \
    xbuf[w][l] = (XIN);                                          \
    float h0 = b1l, h1 = 0.0f;                                   \
    _Pragma("unroll")                                            \
    for (int q = 0; q < 16; ++q) {                               \
        float4 xv = xv4[q];          /* uniform-addr broadcast */\
        h0 = fmaf(W1c[q].x, xv.x, h0);                           \
        h1 = fmaf(W1c[q].y, xv.y, h1);                           \
        h0 = fmaf(W1c[q].z, xv.z, h0);                           \
        h1 = fmaf(W1c[q].w, xv.w, h1);                           \
    }                                                            \
    float a = fast_tanh(h0 + h1);                                \
    abuf[w][l] = a;                                              \
    float p0 = 0.0f, p1 = 0.0f;                                  \
    _Pragma("unroll")                                            \
    for (int q = 0; q < 16; ++q) {                               \
        float4 av = av4[q];                                      \
        p0 = fmaf(av.x, W2r[q].x, p0);                           \
        p1 = fmaf(av.y, W2r[q].y, p1);                           \
        p0 = fmaf(av.z, W2r[q].z, p0);                           \
        p1 = fmaf(av.w, W2r[q].w, p1);                           \
    }                                                            \
    part[pb][l][w] = p0 + p1;                                    \
    BLOCK_SYNC();                                                \
    KOUT = ((part[pb][l][0] + part[pb][l][1]) +                  \
            (part[pb][l][2] + part[pb][l][3])) + b2l;            \
    pb ^= 1;  /* WAR on buffer separated by 2 barriers */        \
} while (0)

__global__ __launch_bounds__(256, 3)
void node_rk4_kernel(const float* __restrict__ y0,
                     const float* __restrict__ t,
                     const float* __restrict__ W1,
                     const float* __restrict__ b1,
                     const float* __restrict__ W2,
                     const float* __restrict__ b2,
                     float* __restrict__ out,
                     int nsteps)
{
    const int row = blockIdx.x;
    const int tid = threadIdx.x;
    const int w   = tid >> 6;        // wave -> hidden slice
    const int l   = tid & 63;        // lane -> dim index / hidden offset
    const int j   = (w << 6) + l;    // owned hidden unit

    __shared__ __align__(16) float xbuf[4][ND];   // wave-private input bcast
    __shared__ __align__(16) float abuf[4][ND];   // wave-private activation bcast
    __shared__ float part[2][ND][5];              // stride-5: conflict-free

    // ---- weight slices -> VGPRs (coalesced loads, compile-time indices) ----
    float4 W1c[16];   // W1[:, j]
    float4 W2r[16];   // W2[64w + jj, l]
    #pragma unroll
    for (int q = 0; q < 16; ++q) {
        W1c[q].x = W1[(4*q + 0) * NH + j];
        W1c[q].y = W1[(4*q + 1) * NH + j];
        W1c[q].z = W1[(4*q + 2) * NH + j];
        W1c[q].w = W1[(4*q + 3) * NH + j];
        W2r[q].x = W2[((w << 6) + 4*q + 0) * ND + l];
        W2r[q].y = W2[((w << 6) + 4*q + 1) * ND + l];
        W2r[q].z = W2[((w << 6) + 4*q + 2) * ND + l];
        W2r[q].w = W2[((w << 6) + 4*q + 3) * ND + l];
    }
    const float b1l = b1[j];
    const float b2l = b2[l];

    const float4* xv4 = reinterpret_cast<const float4*>(&xbuf[w][0]);
    const float4* av4 = reinterpret_cast<const float4*>(&abuf[w][0]);

    float y = y0[row * ND + l];
    if (w == 0) out[row * ND + l] = y;   // step-0 output = y0

    int pb = 0;

    for (int s = 0; s < nsteps; ++s) {
        float h  = t[s + 1] - t[s];      // func is autonomous; only h matters
        float hh = 0.5f * h;
        float k1, k2, k3, k4;
        EVAL(y, k1);
        EVAL(fmaf(hh, k1, y), k2);
        EVAL(fmaf(hh, k2, y), k3);
        EVAL(fmaf(h,  k3, y), k4);
        y = fmaf(h * (1.0f / 6.0f), (k1 + k4) + 2.0f * (k2 + k3), y);
        if (w == 0)                      // waves hold identical y; store once
            out[(size_t)(s + 1) * (NB * ND) + row * ND + l] = y;
    }
}

extern "C" void kernel_launch(void* const* d_in, const int* in_sizes, int n_in,
                              void* d_out, int out_size, void* d_ws, size_t ws_size,
                              hipStream_t stream) {
    const float* y0 = (const float*)d_in[0];
    const float* t  = (const float*)d_in[1];
    const float* W1 = (const float*)d_in[2];
    const float* b1 = (const float*)d_in[3];
    const float* W2 = (const float*)d_in[4];
    const float* b2 = (const float*)d_in[5];
    float* out = (float*)d_out;
    int nsteps = in_sizes[1] - 1;
    hipLaunchKernelGGL(node_rk4_kernel, dim3(NB), dim3(256), 0, stream,
                       y0, t, W1, b1, W2, b2, out, nsteps);
}